// Round 1
// baseline (592.991 us; speedup 1.0000x reference)
//
#include <hip/hip_runtime.h>

#define NNODES 100000
#define NH 8
#define NCH 8
#define OUTD 64    // NH*NCH
#define FDIM 128
#define NEG_SLOPE 0.2f

// ---------------------------------------------------------------------------
// Kernel 1: h = x @ W  (N x 64), plus a_src[n,h] = <h[n,h,:], att_src[h,:]>,
// a_dst likewise. One block = 4 rows, 64 threads (one wave) per row.
// ---------------------------------------------------------------------------
__global__ __launch_bounds__(256) void k_feat(
    const float* __restrict__ x, const float* __restrict__ W,
    const float* __restrict__ att_s, const float* __restrict__ att_d,
    float* __restrict__ h, float* __restrict__ asrc, float* __restrict__ adst)
{
    __shared__ float sW[FDIM * OUTD];   // 32 KB
    __shared__ float sx[4][FDIM];       // 2 KB
    __shared__ float sAs[OUTD], sAd[OUTD];

    for (int i = threadIdx.x; i < FDIM * OUTD; i += 256) sW[i] = W[i];
    if (threadIdx.x < OUTD) {
        sAs[threadIdx.x] = att_s[threadIdx.x];
        sAd[threadIdx.x] = att_d[threadIdx.x];
    }
    int row0 = blockIdx.x * 4;
    for (int i = threadIdx.x; i < 4 * FDIM; i += 256) {
        int r = i >> 7, k = i & (FDIM - 1);
        int row = row0 + r;
        sx[r][k] = (row < NNODES) ? x[(size_t)row * FDIM + k] : 0.f;
    }
    __syncthreads();

    int r = threadIdx.x >> 6;   // row within block (wave-uniform)
    int t = threadIdx.x & 63;   // output column = head*8 + chan
    int row = row0 + r;
    if (row >= NNODES) return;

    float acc = 0.f;
#pragma unroll
    for (int k = 0; k < FDIM; ++k) acc = fmaf(sx[r][k], sW[k * OUTD + t], acc);
    h[(size_t)row * OUTD + t] = acc;

    // reduce within 8-lane groups (one head each)
    float vs = acc * sAs[t];
    float vd = acc * sAd[t];
    vs += __shfl_xor(vs, 1); vs += __shfl_xor(vs, 2); vs += __shfl_xor(vs, 4);
    vd += __shfl_xor(vd, 1); vd += __shfl_xor(vd, 2); vd += __shfl_xor(vd, 4);
    if ((t & 7) == 0) {
        asrc[row * NH + (t >> 3)] = vs;
        adst[row * NH + (t >> 3)] = vd;
    }
}

// ---------------------------------------------------------------------------
// Kernel 2: softmax denominator. One thread per (edge, head).
// No max-subtraction: |e| <= ~30 so exp() is safe in fp32; mathematically
// identical to the reference's stabilized softmax.
// ---------------------------------------------------------------------------
__global__ void k_edge1(const int* __restrict__ ei, int E,
    const float* __restrict__ asrc, const float* __restrict__ adst,
    float* __restrict__ denom)
{
    int tid = blockIdx.x * blockDim.x + threadIdx.x;
    int tot = (E + NNODES) * NH;
    if (tid >= tot) return;
    int e = tid >> 3, hh = tid & 7;
    int s, d;
    if (e < E) { s = ei[e]; d = ei[E + e]; }
    else       { s = d = e - E; }        // self loops appended after edges
    float v = asrc[s * NH + hh] + adst[d * NH + hh];
    v = v > 0.f ? v : NEG_SLOPE * v;
    atomicAdd(&denom[d * NH + hh], __expf(v));
}

// ---------------------------------------------------------------------------
// Kernel 3: weighted message scatter. One thread per (edge, head, chan);
// one wave == one edge (coalesced 256B gather of h[src], 64 contiguous
// fp32 atomics into out[dst]).
// ---------------------------------------------------------------------------
__global__ void k_edge2(const int* __restrict__ ei, int E,
    const float* __restrict__ asrc, const float* __restrict__ adst,
    const float* __restrict__ denom, const float* __restrict__ h,
    float* __restrict__ out)
{
    int tid = blockIdx.x * blockDim.x + threadIdx.x;
    int tot = (E + NNODES) * OUTD;
    if (tid >= tot) return;
    int e = tid >> 6, j = tid & 63;
    int hh = j >> 3;
    int s, d;
    if (e < E) { s = ei[e]; d = ei[E + e]; }
    else       { s = d = e - E; }
    float v = asrc[s * NH + hh] + adst[d * NH + hh];
    v = v > 0.f ? v : NEG_SLOPE * v;
    float alpha = __expf(v) / (denom[d * NH + hh] + 1e-16f);
    atomicAdd(&out[(size_t)d * OUTD + j], alpha * h[(size_t)s * OUTD + j]);
}

// ---------------------------------------------------------------------------
// Kernel 4: out = relu(out + bias)
// ---------------------------------------------------------------------------
__global__ void k_fin(float* __restrict__ out, const float* __restrict__ bias)
{
    int i = blockIdx.x * blockDim.x + threadIdx.x;
    if (i >= NNODES * OUTD) return;
    float v = out[i] + bias[i & 63];
    out[i] = v > 0.f ? v : 0.f;
}

extern "C" void kernel_launch(void* const* d_in, const int* in_sizes, int n_in,
                              void* d_out, int out_size, void* d_ws, size_t ws_size,
                              hipStream_t stream)
{
    const float* x     = (const float*)d_in[0];
    const int*   ei    = (const int*)  d_in[1];   // [2, E] flattened
    const float* W     = (const float*)d_in[2];
    const float* att_s = (const float*)d_in[3];
    const float* att_d = (const float*)d_in[4];
    const float* bias  = (const float*)d_in[5];
    float* out = (float*)d_out;
    int E = in_sizes[1] / 2;

    // workspace layout (fp32)
    float* h     = (float*)d_ws;                       // N*64
    float* asrc  = h    + (size_t)NNODES * OUTD;       // N*8
    float* adst  = asrc + (size_t)NNODES * NH;         // N*8
    float* denom = adst + (size_t)NNODES * NH;         // N*8

    hipMemsetAsync(d_out, 0, (size_t)NNODES * OUTD * sizeof(float), stream);
    hipMemsetAsync(denom, 0, (size_t)NNODES * NH * sizeof(float), stream);

    k_feat<<<(NNODES + 3) / 4, 256, 0, stream>>>(x, W, att_s, att_d, h, asrc, adst);

    int tot1 = (E + NNODES) * NH;
    k_edge1<<<(tot1 + 255) / 256, 256, 0, stream>>>(ei, E, asrc, adst, denom);

    long long tot2 = (long long)(E + NNODES) * OUTD;
    k_edge2<<<(int)((tot2 + 255) / 256), 256, 0, stream>>>(ei, E, asrc, adst, denom, h, out);

    k_fin<<<(NNODES * OUTD + 255) / 256, 256, 0, stream>>>(out, bias);
}

// Round 2
// 421.962 us; speedup vs baseline: 1.4053x; 1.4053x over previous
//
#include <hip/hip_runtime.h>

#define NNODES 100000
#define NH 8
#define NCH 8
#define OUTD 64    // NH*NCH
#define FDIM 128
#define NEG_SLOPE 0.2f
#define SCAN_NB ((NNODES + 255) / 256)   // 391

// ---------------------------------------------------------------------------
// Kernel 1: h = x @ W  (N x 64), plus a_src[n,h] = <h[n,h,:], att_src[h,:]>,
// a_dst likewise. One block = 4 rows, 64 threads (one wave) per row.
// ---------------------------------------------------------------------------
__global__ __launch_bounds__(256) void k_feat(
    const float* __restrict__ x, const float* __restrict__ W,
    const float* __restrict__ att_s, const float* __restrict__ att_d,
    float* __restrict__ h, float* __restrict__ asrc, float* __restrict__ adst)
{
    __shared__ float sW[FDIM * OUTD];   // 32 KB
    __shared__ float sx[4][FDIM];       // 2 KB
    __shared__ float sAs[OUTD], sAd[OUTD];

    for (int i = threadIdx.x; i < FDIM * OUTD; i += 256) sW[i] = W[i];
    if (threadIdx.x < OUTD) {
        sAs[threadIdx.x] = att_s[threadIdx.x];
        sAd[threadIdx.x] = att_d[threadIdx.x];
    }
    int row0 = blockIdx.x * 4;
    for (int i = threadIdx.x; i < 4 * FDIM; i += 256) {
        int r = i >> 7, k = i & (FDIM - 1);
        int row = row0 + r;
        sx[r][k] = (row < NNODES) ? x[(size_t)row * FDIM + k] : 0.f;
    }
    __syncthreads();

    int r = threadIdx.x >> 6;   // row within block (wave-uniform)
    int t = threadIdx.x & 63;   // output column = head*8 + chan
    int row = row0 + r;
    if (row >= NNODES) return;

    float acc = 0.f;
#pragma unroll
    for (int k = 0; k < FDIM; ++k) acc = fmaf(sx[r][k], sW[k * OUTD + t], acc);
    h[(size_t)row * OUTD + t] = acc;

    float vs = acc * sAs[t];
    float vd = acc * sAd[t];
    vs += __shfl_xor(vs, 1); vs += __shfl_xor(vs, 2); vs += __shfl_xor(vs, 4);
    vd += __shfl_xor(vd, 1); vd += __shfl_xor(vd, 2); vd += __shfl_xor(vd, 4);
    if ((t & 7) == 0) {
        asrc[row * NH + (t >> 3)] = vs;
        adst[row * NH + (t >> 3)] = vd;
    }
}

// ---------------------------------------------------------------------------
// CSR build: histogram -> block scan -> top scan -> add + cursor init -> scatter
// ---------------------------------------------------------------------------
__global__ void k_hist(const int* __restrict__ ei, int E, int* __restrict__ deg)
{
    int e = blockIdx.x * blockDim.x + threadIdx.x;
    if (e >= E + NNODES) return;
    int d = (e < E) ? ei[E + e] : (e - E);
    atomicAdd(&deg[d], 1);
}

__global__ __launch_bounds__(256) void k_scan_block(
    const int* __restrict__ deg, int* __restrict__ rowptr, int* __restrict__ bsum)
{
    __shared__ int tmp[256];
    int i = blockIdx.x * 256 + threadIdx.x;
    int v = (i < NNODES) ? deg[i] : 0;
    tmp[threadIdx.x] = v;
    __syncthreads();
    int acc = v;
    for (int off = 1; off < 256; off <<= 1) {
        int t = (threadIdx.x >= off) ? tmp[threadIdx.x - off] : 0;
        __syncthreads();
        acc += t;
        tmp[threadIdx.x] = acc;
        __syncthreads();
    }
    if (i < NNODES) rowptr[i] = acc - v;        // exclusive within block
    if (threadIdx.x == 255) bsum[blockIdx.x] = acc;  // block total
}

__global__ __launch_bounds__(512) void k_scan_top(
    const int* __restrict__ bsum, int* __restrict__ boff, int nb)
{
    __shared__ int tmp[512];
    int v = ((int)threadIdx.x < nb) ? bsum[threadIdx.x] : 0;
    tmp[threadIdx.x] = v;
    __syncthreads();
    int acc = v;
    for (int off = 1; off < 512; off <<= 1) {
        int t = ((int)threadIdx.x >= off) ? tmp[threadIdx.x - off] : 0;
        __syncthreads();
        acc += t;
        tmp[threadIdx.x] = acc;
        __syncthreads();
    }
    if ((int)threadIdx.x < nb) boff[threadIdx.x] = acc - v;   // exclusive
}

__global__ void k_scan_add(int* __restrict__ rowptr, int* __restrict__ cursor,
                           const int* __restrict__ boff)
{
    int i = blockIdx.x * 256 + threadIdx.x;
    if (i >= NNODES) return;
    int r = rowptr[i] + boff[blockIdx.x];
    rowptr[i] = r;
    cursor[i] = r;       // overwrites deg (no longer needed)
}

__global__ void k_scatter(const int* __restrict__ ei, int E,
                          int* __restrict__ cursor, int* __restrict__ esrc)
{
    int e = blockIdx.x * blockDim.x + threadIdx.x;
    if (e >= E + NNODES) return;
    int s, d;
    if (e < E) { s = ei[e]; d = ei[E + e]; }
    else       { s = d = e - E; }
    int pos = atomicAdd(&cursor[d], 1);
    esrc[pos] = s;
}

// ---------------------------------------------------------------------------
// Gather: one wave per destination node. Registers accumulate the softmax
// denominator and the weighted numerator; single coalesced write per row,
// bias + relu fused. After k_scatter, cursor[d] == rowptr[d] + deg[d] == end.
// ---------------------------------------------------------------------------
__global__ __launch_bounds__(256) void k_gather(
    const int* __restrict__ rowptr, const int* __restrict__ rowend,
    const int* __restrict__ esrc,
    const float* __restrict__ h, const float* __restrict__ asrc,
    const float* __restrict__ adst, const float* __restrict__ bias,
    float* __restrict__ out)
{
    int node = (blockIdx.x * 256 + threadIdx.x) >> 6;
    if (node >= NNODES) return;
    int lane = threadIdx.x & 63;
    int hh = lane >> 3;

    float adh = adst[node * NH + hh];
    int start = rowptr[node];
    int end   = rowend[node];

    float num = 0.f, den = 0.f;
    for (int base = start; base < end; base += 64) {
        int cnt = end - base; if (cnt > 64) cnt = 64;
        int sj = (base + lane < end) ? esrc[base + lane] : 0;  // coalesced batch
        for (int k = 0; k < cnt; ++k) {
            int s = __shfl(sj, k);
            float ev = asrc[s * NH + hh] + adh;
            ev = ev > 0.f ? ev : NEG_SLOPE * ev;
            float ex = __expf(ev);
            num = fmaf(ex, h[(size_t)s * OUTD + lane], num);
            den += ex;
        }
    }
    float v = num / (den + 1e-16f) + bias[lane];
    out[(size_t)node * OUTD + lane] = v > 0.f ? v : 0.f;
}

extern "C" void kernel_launch(void* const* d_in, const int* in_sizes, int n_in,
                              void* d_out, int out_size, void* d_ws, size_t ws_size,
                              hipStream_t stream)
{
    const float* x     = (const float*)d_in[0];
    const int*   ei    = (const int*)  d_in[1];   // [2, E] flattened
    const float* W     = (const float*)d_in[2];
    const float* att_s = (const float*)d_in[3];
    const float* att_d = (const float*)d_in[4];
    const float* bias  = (const float*)d_in[5];
    float* out = (float*)d_out;
    int E = in_sizes[1] / 2;
    int tot = E + NNODES;

    // workspace layout
    float* h      = (float*)d_ws;                       // N*64 f32
    float* asrc   = h    + (size_t)NNODES * OUTD;       // N*8
    float* adst   = asrc + (size_t)NNODES * NH;         // N*8
    int*   rowptr = (int*)(adst + (size_t)NNODES * NH); // N
    int*   cursor = rowptr + NNODES;                    // N (deg, then cursor/end)
    int*   bsum   = cursor + NNODES;                    // SCAN_NB
    int*   boff   = bsum + 512;                         // SCAN_NB
    int*   esrc   = boff + 512;                         // E+N

    hipMemsetAsync(cursor, 0, NNODES * sizeof(int), stream);  // deg = 0

    k_feat<<<(NNODES + 3) / 4, 256, 0, stream>>>(x, W, att_s, att_d, h, asrc, adst);

    k_hist<<<(tot + 255) / 256, 256, 0, stream>>>(ei, E, cursor);
    k_scan_block<<<SCAN_NB, 256, 0, stream>>>(cursor, rowptr, bsum);
    k_scan_top<<<1, 512, 0, stream>>>(bsum, boff, SCAN_NB);
    k_scan_add<<<SCAN_NB, 256, 0, stream>>>(rowptr, cursor, boff);
    k_scatter<<<(tot + 255) / 256, 256, 0, stream>>>(ei, E, cursor, esrc);

    k_gather<<<(NNODES * 64 + 255) / 256, 256, 0, stream>>>(
        rowptr, cursor, esrc, h, asrc, adst, bias, out);
}